// Round 5
// baseline (3470.628 us; speedup 1.0000x reference)
//
#include <hip/hip_runtime.h>
#include <hip/hip_bf16.h>
#include <cstdint>

#define DEVI __device__ __forceinline__

typedef __attribute__((ext_vector_type(8))) short bf16x8_t;   // 8 bf16 in 4 VGPRs
typedef __attribute__((ext_vector_type(4))) float f32x4_t;    // MFMA C/D

DEVI float bf2f(unsigned short u) {
    union { uint32_t i; float f; } v; v.i = ((uint32_t)u) << 16; return v.f;
}
DEVI unsigned short f2bf(float f) {
    union { float f; uint32_t i; } v; v.f = f;
    uint32_t i = v.i;
    uint32_t r = (i + 0x7FFFu + ((i >> 16) & 1u)) >> 16;   // RNE
    return (unsigned short)r;
}

DEVI f32x4_t mfma16(bf16x8_t a, bf16x8_t b, f32x4_t c) {
    return __builtin_amdgcn_mfma_f32_16x16x32_bf16(a, b, c, 0, 0, 0);
}

#define GL2LDS(g, l) __builtin_amdgcn_global_load_lds( \
    (const __attribute__((address_space(1))) void*)(g), \
    (__attribute__((address_space(3))) void*)(l), 16, 0, 0)

// ---------------------------------------------------------------- embedding
__global__ void k_embed(const int* __restrict__ ids, const float* __restrict__ wte,
                        const float* __restrict__ wpe, float* __restrict__ h) {
    int m = blockIdx.x;            // 0..4095  (b*1024 + s)
    int s = m & 1023;
    int id = ids[m];
    const float* te = wte + (size_t)id * 768;
    const float* pe = wpe + (size_t)s * 768;
    float* out = h + (size_t)m * 768;
    for (int d = threadIdx.x; d < 768; d += 256) out[d] = te[d] + pe[d];
}

// ---------------------------------------------------------------- layernorm (plain)
__global__ void k_ln(const float* __restrict__ h, const float* __restrict__ w,
                     const float* __restrict__ b, unsigned short* __restrict__ x) {
    int m = blockIdx.x;
    const float* row = h + (size_t)m * 768;
    int t = threadIdx.x;
    float v[3];
    float s = 0.f, ss = 0.f;
#pragma unroll
    for (int i = 0; i < 3; i++) {
        v[i] = row[t + i * 256];
        s += v[i]; ss += v[i] * v[i];
    }
#pragma unroll
    for (int o = 32; o > 0; o >>= 1) { s += __shfl_down(s, o); ss += __shfl_down(ss, o); }
    __shared__ float red[8];
    int wid = t >> 6, lane = t & 63;
    if (lane == 0) { red[wid] = s; red[4 + wid] = ss; }
    __syncthreads();
    if (t == 0) {
        float S = red[0] + red[1] + red[2] + red[3];
        float SS = red[4] + red[5] + red[6] + red[7];
        float mean = S * (1.f / 768.f);
        float var = SS * (1.f / 768.f) - mean * mean;
        red[0] = mean; red[1] = rsqrtf(var + 1e-5f);
    }
    __syncthreads();
    float mean = red[0], rst = red[1];
    unsigned short* xo = x + (size_t)m * 768;
#pragma unroll
    for (int i = 0; i < 3; i++) {
        int d = t + i * 256;
        xo[d] = f2bf((v[i] - mean) * rst * w[d] + b[d]);
    }
}

// --------------------------------------- fused: h += p0+p1+bias ; x = LN(h)
__global__ void k_ln_red(const float* __restrict__ part, const float* __restrict__ ab,
                         const float* __restrict__ w, const float* __restrict__ b,
                         float* __restrict__ h, unsigned short* __restrict__ x) {
    int m = blockIdx.x;
    const float* p0 = part + (size_t)m * 768;
    const float* p1 = part + 4096ull * 768 + (size_t)m * 768;
    float* hr = h + (size_t)m * 768;
    int t = threadIdx.x;
    float v[3];
    float s = 0.f, ss = 0.f;
#pragma unroll
    for (int i = 0; i < 3; i++) {
        int d = t + i * 256;
        float val = hr[d] + p0[d] + p1[d] + ab[d];
        v[i] = val;
        s += val; ss += val * val;
    }
#pragma unroll
    for (int o = 32; o > 0; o >>= 1) { s += __shfl_down(s, o); ss += __shfl_down(ss, o); }
    __shared__ float red[8];
    int wid = t >> 6, lane = t & 63;
    if (lane == 0) { red[wid] = s; red[4 + wid] = ss; }
    __syncthreads();
    if (t == 0) {
        float S = red[0] + red[1] + red[2] + red[3];
        float SS = red[4] + red[5] + red[6] + red[7];
        float mean = S * (1.f / 768.f);
        float var = SS * (1.f / 768.f) - mean * mean;
        red[0] = mean; red[1] = rsqrtf(var + 1e-5f);
    }
    __syncthreads();
    float mean = red[0], rst = red[1];
    unsigned short* xo = x + (size_t)m * 768;
#pragma unroll
    for (int i = 0; i < 3; i++) {
        int d = t + i * 256;
        hr[d] = v[i];
        xo[d] = f2bf((v[i] - mean) * rst * w[d] + b[d]);
    }
}

// ------------------------------------------------- transpose fp32[K][N] -> bf16[Npad][K]
__global__ void k_transpose(const float* __restrict__ W, unsigned short* __restrict__ Bt,
                            int K, int N, int Npad) {
    __shared__ float tile[32][33];
    int tx = threadIdx.x, ty = threadIdx.y;     // (32, 8)
    int n0 = blockIdx.x * 32, k0 = blockIdx.y * 32;
    size_t l = blockIdx.z;
    W += l * (size_t)K * N;
    Bt += l * (size_t)Npad * K;
#pragma unroll
    for (int i = 0; i < 4; i++) {
        int k = k0 + ty + i * 8;
        int n = n0 + tx;
        tile[ty + i * 8][tx] = (n < N) ? W[(size_t)k * N + n] : 0.f;
    }
    __syncthreads();
#pragma unroll
    for (int i = 0; i < 4; i++) {
        int n = n0 + ty + i * 8;
        Bt[(size_t)n * K + k0 + tx] = f2bf(tile[tx][ty + i * 8]);
    }
}

// ---------------------------------------------------------------- GEMM (mid-size)
// C[M,N] = A[M,K](bf16) x Bt[N,K](bf16)^T. 256 thr, 4 waves 2x2, BM x 128 tile,
// BK=32, double-buffered global_load_lds prefetch, one barrier per K-step.
// SPLITK: blockIdx.z = K-chunk, f32 partials to out + z*M*N.
// QKVV: V-columns (>=1536) written transposed to vt[bh][d][key].
template <int BM, int BIAS, int GELU, int OUTBF16, int SPLITK, int QKVV>
__launch_bounds__(256, 2)
__global__ void k_gemm(const unsigned short* __restrict__ A,
                       const unsigned short* __restrict__ Bt,
                       const float* __restrict__ bias,
                       void* __restrict__ out,
                       unsigned short* __restrict__ vtout,
                       int M, int N, int K) {
    constexpr int MF = BM / 32;                       // m-frags per wave
    constexpr int HALF = (BM + 128) * 64;             // bytes per stage buffer
    __shared__ char smem_raw[2 * HALF];

    int t = threadIdx.x;
    int bm = blockIdx.x, bn = blockIdx.y;
    int kc = (SPLITK > 1) ? blockIdx.z : 0;
    int KC = K / SPLITK;

    int rowA0 = bm * BM, rowB0 = bn * 128;
    int lane = t & 63, w = t >> 6;
    int wr = w >> 1, wc = w & 1;

    const unsigned short* ga0 = A  + (size_t)(rowA0 + (t >> 2)) * K + kc * KC + (t & 3) * 8;
    const unsigned short* ga1 = ga0 + (size_t)64 * K;
    const unsigned short* gb0 = Bt + (size_t)(rowB0 + (t >> 2)) * K + kc * KC + (t & 3) * 8;
    const unsigned short* gb1 = gb0 + (size_t)64 * K;

    auto stage = [&](int buf, int ktile) {
        char* dst = smem_raw + buf * HALF + t * 16;
        int kt = ktile * 32;
        GL2LDS(ga0 + kt, dst);
        if constexpr (BM == 128) GL2LDS(ga1 + kt, dst + 4096);
        char* dstB = dst + BM * 64;
        GL2LDS(gb0 + kt, dstB);
        GL2LDS(gb1 + kt, dstB + 4096);
    };

    f32x4_t acc[MF][4] = {};

    int rA = wr * (BM / 2) + (lane & 15);
    int rB = wc * 64 + (lane & 15);
    int kofs = (lane >> 4) * 8;

    const int NT = KC / 32;
    stage(0, 0);
    __syncthreads();
    int cur = 0;
    for (int kt = 0; kt < NT; kt++) {
        if (kt + 1 < NT) stage(cur ^ 1, kt + 1);   // prefetch overlaps compute
        const unsigned short* As = (const unsigned short*)(smem_raw + cur * HALF);
        const unsigned short* Bs = As + BM * 32;
        bf16x8_t a[MF], b[4];
#pragma unroll
        for (int m = 0; m < MF; m++)
            a[m] = *reinterpret_cast<const bf16x8_t*>(As + (rA + m * 16) * 32 + kofs);
#pragma unroll
        for (int n = 0; n < 4; n++)
            b[n] = *reinterpret_cast<const bf16x8_t*>(Bs + (rB + n * 16) * 32 + kofs);
#pragma unroll
        for (int m = 0; m < MF; m++)
#pragma unroll
            for (int n = 0; n < 4; n++)
                acc[m][n] = mfma16(a[m], b[n], acc[m][n]);
        __syncthreads();              // drains prefetch + protects buf reuse
        cur ^= 1;
    }

    if constexpr (OUTBF16) {
        int colBase = bn * 128 + wc * 64 + (lane & 15);
        int rowBase = bm * BM + wr * (BM / 2) + ((lane >> 4) << 2);
#pragma unroll
        for (int n = 0; n < 4; n++) {
            int col = colBase + n * 16;
            float bv = 0.f;
            if (BIAS) bv = bias[col];
#pragma unroll
            for (int m = 0; m < MF; m++) {
                int row0 = rowBase + m * 16;
#pragma unroll
                for (int r = 0; r < 4; r++) {
                    int row = row0 + r;
                    float v = acc[m][n][r] + bv;
                    if (GELU) v = 0.5f * v * (1.f + erff(v * 0.70710678118f));
                    if (QKVV && col >= 1536) {
                        // write V transposed: vt[(b*12+h)][d][key]
                        int bb = row >> 10, key = row & 1023;
                        int hh = (col - 1536) >> 6, d = (col - 1536) & 63;
                        vtout[((size_t)((bb * 12 + hh) * 64 + d)) * 1024 + key] = f2bf(v);
                    } else {
                        ((unsigned short*)out)[(size_t)row * N + col] = f2bf(v);
                    }
                }
            }
        }
    } else {
        // f32 partials: LDS epilogue transpose, 256B-contiguous float4 stores.
        auto epi = (float (*)[16][65])smem_raw;
        float* op_base = (float*)out + (size_t)kc * M * N;
        int rowBase0 = bm * BM + wr * (BM / 2);
        int colBase0 = bn * 128 + wc * 64;
#pragma unroll
        for (int m = 0; m < MF; m++) {
#pragma unroll
            for (int n = 0; n < 4; n++)
#pragma unroll
                for (int r = 0; r < 4; r++)
                    epi[w][(lane >> 4) * 4 + r][n * 16 + (lane & 15)] = acc[m][n][r];
            __syncthreads();
#pragma unroll
            for (int rr = 0; rr < 4; rr++) {
                int lr = (lane >> 4) * 4 + rr;
                int grow = rowBase0 + m * 16 + lr;
                int gcol = colBase0 + (lane & 15) * 4;
                float4 v4 = *reinterpret_cast<float4*>(&epi[w][lr][(lane & 15) * 4]);
                *reinterpret_cast<float4*>(op_base + (size_t)grow * N + gcol) = v4;
            }
            __syncthreads();
        }
    }
}

// ---------------------------------------------------------------- lm-head GEMM
// 256x256 tile, BK=64, 512 thr (8 waves, 2M x 4N), deep pipeline:
// counted vmcnt(8) spanning raw s_barriers (T4), LDS XOR swizzle on reads
// with pre-swizzled global source (T2 + rule#21), setprio around MFMA (T5).
__launch_bounds__(512, 1)
__global__ void k_lm(const unsigned short* __restrict__ A,
                     const unsigned short* __restrict__ Bt,
                     float* __restrict__ out) {
    constexpr int K = 768;
    constexpr int NT = K / 64;                 // 12 K-tiles
    __shared__ char smem[131072];              // 2 x (A 32KB | B 32KB)

    int t = threadIdx.x;
    int bm = blockIdx.x, bn = blockIdx.y;      // natural order, bm fastest
    int lane = t & 63, w = t >> 6;
    int wm = w >> 2, wn = w & 3;               // 2 x 4 waves
    int q = lane >> 4, l15 = lane & 15, l7 = lane & 7;

    int srow = t >> 3;                         // 0..63 per issue
    int sslot = (t & 7) ^ (srow & 7);
    const unsigned short* gA = A  + (size_t)(bm * 256 + srow) * K + sslot * 8;
    const unsigned short* gB = Bt + (size_t)(bn * 256 + srow) * K + sslot * 8;

    auto stage = [&](int buf, int ktile) {
        char* dst = smem + buf * 65536 + t * 16;
        int ko = ktile * 64;
#pragma unroll
        for (int i = 0; i < 4; i++)
            GL2LDS(gA + (size_t)(i * 64) * K + ko, dst + i * 8192);
#pragma unroll
        for (int i = 0; i < 4; i++)
            GL2LDS(gB + (size_t)(i * 64) * K + ko, dst + 32768 + i * 8192);
    };

    f32x4_t acc[8][4] = {};

    stage(0, 0);
    int cur = 0;
    for (int kt = 0; kt < NT; kt++) {
        if (kt + 1 < NT) {
            stage(cur ^ 1, kt + 1);
            asm volatile("s_waitcnt vmcnt(8)" ::: "memory");
        } else {
            asm volatile("s_waitcnt vmcnt(0)" ::: "memory");
        }
        __builtin_amdgcn_s_barrier();
        asm volatile("" ::: "memory");
        const char* Ab = smem + cur * 65536;
        const char* Bb = Ab + 32768;

        bf16x8_t bfr[4][2];
#pragma unroll
        for (int nf = 0; nf < 4; nf++)
#pragma unroll
            for (int ks = 0; ks < 2; ks++) {
                int row = wn * 64 + nf * 16 + l15;
                int slot = (ks * 4 + q) ^ l7;
                bfr[nf][ks] = *reinterpret_cast<const bf16x8_t*>(Bb + row * 128 + slot * 16);
            }
#pragma unroll
        for (int p = 0; p < 4; p++) {
            bf16x8_t afr[2][2];
#pragma unroll
            for (int mi = 0; mi < 2; mi++)
#pragma unroll
                for (int ks = 0; ks < 2; ks++) {
                    int row = wm * 128 + (p * 2 + mi) * 16 + l15;
                    int slot = (ks * 4 + q) ^ l7;
                    afr[mi][ks] = *reinterpret_cast<const bf16x8_t*>(Ab + row * 128 + slot * 16);
                }
            asm volatile("s_waitcnt lgkmcnt(0)" ::: "memory");
            __builtin_amdgcn_sched_barrier(0);
            __builtin_amdgcn_s_setprio(1);
#pragma unroll
            for (int mi = 0; mi < 2; mi++)
#pragma unroll
                for (int nf = 0; nf < 4; nf++)
#pragma unroll
                    for (int ks = 0; ks < 2; ks++)
                        acc[p * 2 + mi][nf] = mfma16(afr[mi][ks], bfr[nf][ks], acc[p * 2 + mi][nf]);
            __builtin_amdgcn_s_setprio(0);
        }
        asm volatile("" ::: "memory");
        __builtin_amdgcn_s_barrier();
        cur ^= 1;
    }

    float* epi = (float*)smem + w * (16 * 68);
#pragma unroll
    for (int mf = 0; mf < 8; mf++) {
#pragma unroll
        for (int nf = 0; nf < 4; nf++)
#pragma unroll
            for (int r = 0; r < 4; r++)
                epi[(q * 4 + r) * 68 + nf * 16 + l15] = acc[mf][nf][r];
        asm volatile("s_waitcnt lgkmcnt(0)" ::: "memory");
#pragma unroll
        for (int rr = 0; rr < 4; rr++) {
            int lr = q * 4 + rr;
            int grow = bm * 256 + wm * 128 + mf * 16 + lr;
            int col0 = bn * 256 + wn * 64 + l15;
            float* op = out + (size_t)grow * 50257 + col0;
#pragma unroll
            for (int e = 0; e < 4; e++) {
                if (col0 + e * 16 < 50257) op[e * 16] = epi[lr * 68 + l15 + e * 16];
            }
        }
        asm volatile("s_waitcnt lgkmcnt(0)" ::: "memory");
    }
}

// ---------------------------------------------------------------- flash attention
// grid (16 q-tiles, 48 bh), 256 thr, 4 independent waves, NO barriers.
// K read direct from qkvb (L2-resident); V read pre-transposed from vt.
__launch_bounds__(256, 2)
__global__ void k_attn(const unsigned short* __restrict__ qkv,
                       const unsigned short* __restrict__ vt,
                       unsigned short* __restrict__ y) {
    __shared__ unsigned short Ps[4][16 * 72];    // per-wave P rows, stride 72

    int bh = blockIdx.y;
    int b = bh / 12, h = bh % 12;
    int qt = blockIdx.x;
    int t = threadIdx.x, lane = t & 63, w = t >> 6;
    const size_t ldq = 2304;
    const unsigned short* base = qkv + (size_t)b * 1024 * ldq + h * 64;
    const unsigned short* vbase = vt + (size_t)bh * 64 * 1024;

    bf16x8_t qf[2];
    int qrow = qt * 64 + w * 16 + (lane & 15);
#pragma unroll
    for (int kb = 0; kb < 2; kb++)
        qf[kb] = *reinterpret_cast<const bf16x8_t*>(base + (size_t)qrow * ldq + kb * 32 + (lane >> 4) * 8);

    f32x4_t o[4] = {};
    float mrow[4], lsum[4];
#pragma unroll
    for (int r = 0; r < 4; r++) { mrow[r] = -1e30f; lsum[r] = 0.f; }
    const float scale = 0.125f;

    for (int kt = 0; kt < 16; kt++) {
        f32x4_t s[4] = {};
#pragma unroll
        for (int kb = 0; kb < 2; kb++) {
#pragma unroll
            for (int n = 0; n < 4; n++) {
                const unsigned short* kp = base + 768 +
                    (size_t)(kt * 64 + n * 16 + (lane & 15)) * ldq + kb * 32 + (lane >> 4) * 8;
                bf16x8_t kf = *reinterpret_cast<const bf16x8_t*>(kp);
                s[n] = mfma16(qf[kb], kf, s[n]);
            }
        }
        float corr[4];
#pragma unroll
        for (int r = 0; r < 4; r++) {
            float mx = fmaxf(fmaxf(s[0][r], s[1][r]), fmaxf(s[2][r], s[3][r]));
#pragma unroll
            for (int o2 = 1; o2 < 16; o2 <<= 1) mx = fmaxf(mx, __shfl_xor(mx, o2));
            float mnew = fmaxf(mrow[r], mx * scale);
            corr[r] = __expf(mrow[r] - mnew);
            mrow[r] = mnew;
        }
        float psum[4] = {0.f, 0.f, 0.f, 0.f};
#pragma unroll
        for (int n = 0; n < 4; n++) {
#pragma unroll
            for (int r = 0; r < 4; r++) {
                float p = __expf(s[n][r] * scale - mrow[r]);
                psum[r] += p;
                int prow = (lane >> 4) * 4 + r;
                Ps[w][prow * 72 + n * 16 + (lane & 15)] = f2bf(p);
            }
        }
#pragma unroll
        for (int r = 0; r < 4; r++) {
            float ps = psum[r];
#pragma unroll
            for (int o2 = 1; o2 < 16; o2 <<= 1) ps += __shfl_xor(ps, o2);
            lsum[r] = lsum[r] * corr[r] + ps;
#pragma unroll
            for (int n = 0; n < 4; n++) o[n][r] *= corr[r];
        }
        // O += P V   (V^T fragments straight from global vt, wave-local LDS for P)
#pragma unroll
        for (int kb = 0; kb < 2; kb++) {
            bf16x8_t pf = *reinterpret_cast<const bf16x8_t*>(
                &Ps[w][(lane & 15) * 72 + kb * 32 + (lane >> 4) * 8]);
#pragma unroll
            for (int n = 0; n < 4; n++) {
                const unsigned short* vp = vbase + (size_t)(n * 16 + (lane & 15)) * 1024
                                         + kt * 64 + kb * 32 + (lane >> 4) * 8;
                bf16x8_t vf = *reinterpret_cast<const bf16x8_t*>(vp);
                o[n] = mfma16(pf, vf, o[n]);
            }
        }
    }
#pragma unroll
    for (int n = 0; n < 4; n++) {
#pragma unroll
        for (int r = 0; r < 4; r++) {
            float val = o[n][r] / lsum[r];
            int row = qt * 64 + w * 16 + (lane >> 4) * 4 + r;
            y[((size_t)(b * 1024 + row)) * 768 + h * 64 + n * 16 + (lane & 15)] = f2bf(val);
        }
    }
}

// ---------------------------------------------------------------- host
extern "C" void kernel_launch(void* const* d_in, const int* in_sizes, int n_in,
                              void* d_out, int out_size, void* d_ws, size_t ws_size,
                              hipStream_t stream) {
    const int*   ids   = (const int*)d_in[0];
    const float* wte   = (const float*)d_in[1];
    const float* wpe   = (const float*)d_in[2];
    const float* ln1w  = (const float*)d_in[3];
    const float* ln1b  = (const float*)d_in[4];
    const float* attnw = (const float*)d_in[5];
    const float* attnb = (const float*)d_in[6];
    const float* atpw  = (const float*)d_in[7];
    const float* atpb  = (const float*)d_in[8];
    const float* ln2w  = (const float*)d_in[9];
    const float* ln2b  = (const float*)d_in[10];
    const float* fcw   = (const float*)d_in[11];
    const float* fcb   = (const float*)d_in[12];
    const float* pjw   = (const float*)d_in[13];
    const float* pjb   = (const float*)d_in[14];
    const float* lnfw  = (const float*)d_in[15];
    const float* lnfb  = (const float*)d_in[16];
    const float* lmw   = (const float*)d_in[17];
    float* out = (float*)d_out;

    char* ws = (char*)d_ws;
    size_t off = 0;
    auto alloc = [&](size_t bytes) -> void* {
        void* p = ws + off;
        off += (bytes + 255) & ~(size_t)255;
        return p;
    };
    float*          h      = (float*)alloc(4096ull * 768 * 4);
    unsigned short* x      = (unsigned short*)alloc(4096ull * 768 * 2);
    unsigned short* qkvb   = (unsigned short*)alloc(4096ull * 2304 * 2);
    unsigned short* vtb    = (unsigned short*)alloc(48ull * 64 * 1024 * 2);
    unsigned short* y      = (unsigned short*)alloc(4096ull * 768 * 2);
    unsigned short* u      = (unsigned short*)alloc(4096ull * 3072 * 2);
    float*          part   = (float*)alloc(2ull * 4096 * 768 * 4);
    unsigned short* attnwT = (unsigned short*)alloc(12ull * 2304 * 768 * 2);
    unsigned short* atpwT  = (unsigned short*)alloc(12ull * 768 * 768 * 2);
    unsigned short* fcwT   = (unsigned short*)alloc(12ull * 3072 * 768 * 2);
    unsigned short* pjwT   = (unsigned short*)alloc(12ull * 768 * 3072 * 2);
    unsigned short* lmwT   = (unsigned short*)alloc(50432ull * 768 * 2);

    dim3 tb(32, 8);
    k_transpose<<<dim3(2304 / 32, 768 / 32, 12), tb, 0, stream>>>(attnw, attnwT, 768, 2304, 2304);
    k_transpose<<<dim3(768 / 32, 768 / 32, 12), tb, 0, stream>>>(atpw, atpwT, 768, 768, 768);
    k_transpose<<<dim3(3072 / 32, 768 / 32, 12), tb, 0, stream>>>(fcw, fcwT, 768, 3072, 3072);
    k_transpose<<<dim3(768 / 32, 3072 / 32, 12), tb, 0, stream>>>(pjw, pjwT, 3072, 768, 768);
    k_transpose<<<dim3(50432 / 32, 768 / 32, 1), tb, 0, stream>>>(lmw, lmwT, 768, 50257, 50432);

    k_embed<<<4096, 256, 0, stream>>>(ids, wte, wpe, h);
    k_ln<<<4096, 256, 0, stream>>>(h, ln1w, ln1b, x);     // layer-0 ln1

    for (int l = 0; l < 12; l++) {
        // qkv: Q,K -> qkvb ; V -> vtb (transposed in epilogue)
        k_gemm<128, 1, 0, 1, 1, 1><<<dim3(32, 18), 256, 0, stream>>>(
            x, attnwT + (size_t)l * 2304 * 768, attnb + l * 2304, qkvb, vtb,
            4096, 2304, 768);
        k_attn<<<dim3(16, 48), 256, 0, stream>>>(qkvb, vtb, y);
        // atp: split-K=2 f32 partials
        k_gemm<64, 0, 0, 0, 2, 0><<<dim3(64, 6, 2), 256, 0, stream>>>(
            y, atpwT + (size_t)l * 768 * 768, nullptr, part, nullptr,
            4096, 768, 768);
        k_ln_red<<<4096, 256, 0, stream>>>(part, atpb + l * 768,
            ln2w + l * 768, ln2b + l * 768, h, x);
        // fc
        k_gemm<128, 1, 1, 1, 1, 0><<<dim3(32, 24), 256, 0, stream>>>(
            x, fcwT + (size_t)l * 3072 * 768, fcb + l * 3072, u, nullptr,
            4096, 3072, 768);
        // pj: split-K=2 f32 partials
        k_gemm<64, 0, 0, 0, 2, 0><<<dim3(64, 6, 2), 256, 0, stream>>>(
            u, pjwT + (size_t)l * 768 * 3072, nullptr, part, nullptr,
            4096, 768, 3072);
        const float* nw = (l < 11) ? ln1w + (l + 1) * 768 : lnfw;
        const float* nb = (l < 11) ? ln1b + (l + 1) * 768 : lnfb;
        k_ln_red<<<4096, 256, 0, stream>>>(part, pjb + l * 768, nw, nb, h, x);
    }
    k_lm<<<dim3(16, 197), 512, 0, stream>>>(x, lmwT, out);
}

// Round 6
// 3148.792 us; speedup vs baseline: 1.1022x; 1.1022x over previous
//
#include <hip/hip_runtime.h>
#include <hip/hip_bf16.h>
#include <cstdint>

#define DEVI __device__ __forceinline__

typedef __attribute__((ext_vector_type(8))) short bf16x8_t;   // 8 bf16 in 4 VGPRs
typedef __attribute__((ext_vector_type(4))) float f32x4_t;    // MFMA C/D

DEVI float bf2f(unsigned short u) {
    union { uint32_t i; float f; } v; v.i = ((uint32_t)u) << 16; return v.f;
}
DEVI unsigned short f2bf(float f) {
    union { float f; uint32_t i; } v; v.f = f;
    uint32_t i = v.i;
    uint32_t r = (i + 0x7FFFu + ((i >> 16) & 1u)) >> 16;   // RNE
    return (unsigned short)r;
}

DEVI f32x4_t mfma16(bf16x8_t a, bf16x8_t b, f32x4_t c) {
    return __builtin_amdgcn_mfma_f32_16x16x32_bf16(a, b, c, 0, 0, 0);
}

#define GL2LDS(g, l) __builtin_amdgcn_global_load_lds( \
    (const __attribute__((address_space(1))) void*)(g), \
    (__attribute__((address_space(3))) void*)(l), 16, 0, 0)

// ---------------------------------------------------------------- embedding
__global__ void k_embed(const int* __restrict__ ids, const float* __restrict__ wte,
                        const float* __restrict__ wpe, float* __restrict__ h) {
    int m = blockIdx.x;            // 0..4095  (b*1024 + s)
    int s = m & 1023;
    int id = ids[m];
    const float* te = wte + (size_t)id * 768;
    const float* pe = wpe + (size_t)s * 768;
    float* out = h + (size_t)m * 768;
    for (int d = threadIdx.x; d < 768; d += 256) out[d] = te[d] + pe[d];
}

// ---------------------------------------------------------------- layernorm (plain)
__global__ void k_ln(const float* __restrict__ h, const float* __restrict__ w,
                     const float* __restrict__ b, unsigned short* __restrict__ x) {
    int m = blockIdx.x;
    const float* row = h + (size_t)m * 768;
    int t = threadIdx.x;
    float v[3];
    float s = 0.f, ss = 0.f;
#pragma unroll
    for (int i = 0; i < 3; i++) {
        v[i] = row[t + i * 256];
        s += v[i]; ss += v[i] * v[i];
    }
#pragma unroll
    for (int o = 32; o > 0; o >>= 1) { s += __shfl_down(s, o); ss += __shfl_down(ss, o); }
    __shared__ float red[8];
    int wid = t >> 6, lane = t & 63;
    if (lane == 0) { red[wid] = s; red[4 + wid] = ss; }
    __syncthreads();
    if (t == 0) {
        float S = red[0] + red[1] + red[2] + red[3];
        float SS = red[4] + red[5] + red[6] + red[7];
        float mean = S * (1.f / 768.f);
        float var = SS * (1.f / 768.f) - mean * mean;
        red[0] = mean; red[1] = rsqrtf(var + 1e-5f);
    }
    __syncthreads();
    float mean = red[0], rst = red[1];
    unsigned short* xo = x + (size_t)m * 768;
#pragma unroll
    for (int i = 0; i < 3; i++) {
        int d = t + i * 256;
        xo[d] = f2bf((v[i] - mean) * rst * w[d] + b[d]);
    }
}

// --------------------------------------- fused: h += p0+p1+bias ; x = LN(h)
__global__ void k_ln_red(const float* __restrict__ part, const float* __restrict__ ab,
                         const float* __restrict__ w, const float* __restrict__ b,
                         float* __restrict__ h, unsigned short* __restrict__ x) {
    int m = blockIdx.x;
    const float* p0 = part + (size_t)m * 768;
    const float* p1 = part + 4096ull * 768 + (size_t)m * 768;
    float* hr = h + (size_t)m * 768;
    int t = threadIdx.x;
    float v[3];
    float s = 0.f, ss = 0.f;
#pragma unroll
    for (int i = 0; i < 3; i++) {
        int d = t + i * 256;
        float val = hr[d] + p0[d] + p1[d] + ab[d];
        v[i] = val;
        s += val; ss += val * val;
    }
#pragma unroll
    for (int o = 32; o > 0; o >>= 1) { s += __shfl_down(s, o); ss += __shfl_down(ss, o); }
    __shared__ float red[8];
    int wid = t >> 6, lane = t & 63;
    if (lane == 0) { red[wid] = s; red[4 + wid] = ss; }
    __syncthreads();
    if (t == 0) {
        float S = red[0] + red[1] + red[2] + red[3];
        float SS = red[4] + red[5] + red[6] + red[7];
        float mean = S * (1.f / 768.f);
        float var = SS * (1.f / 768.f) - mean * mean;
        red[0] = mean; red[1] = rsqrtf(var + 1e-5f);
    }
    __syncthreads();
    float mean = red[0], rst = red[1];
    unsigned short* xo = x + (size_t)m * 768;
#pragma unroll
    for (int i = 0; i < 3; i++) {
        int d = t + i * 256;
        hr[d] = v[i];
        xo[d] = f2bf((v[i] - mean) * rst * w[d] + b[d]);
    }
}

// ------------------------------------------------- transpose fp32[K][N] -> bf16[Npad][K]
__global__ void k_transpose(const float* __restrict__ W, unsigned short* __restrict__ Bt,
                            int K, int N, int Npad) {
    __shared__ float tile[32][33];
    int tx = threadIdx.x, ty = threadIdx.y;     // (32, 8)
    int n0 = blockIdx.x * 32, k0 = blockIdx.y * 32;
    size_t l = blockIdx.z;
    W += l * (size_t)K * N;
    Bt += l * (size_t)Npad * K;
#pragma unroll
    for (int i = 0; i < 4; i++) {
        int k = k0 + ty + i * 8;
        int n = n0 + tx;
        tile[ty + i * 8][tx] = (n < N) ? W[(size_t)k * N + n] : 0.f;
    }
    __syncthreads();
#pragma unroll
    for (int i = 0; i < 4; i++) {
        int n = n0 + ty + i * 8;
        Bt[(size_t)n * K + k0 + tx] = f2bf(tile[tx][ty + i * 8]);
    }
}

// ---------------------------------------------------------------- GEMM (mid-size)
// C[M,N] = A[M,K](bf16) x Bt[N,K](bf16)^T. 256 thr, 4 waves 2x2, BM x 128 tile,
// BK=32, double-buffered global_load_lds prefetch, one barrier per K-step.
// OUTBF16: bias/gelu epilogue, bf16 store.
// else: f32 partials to out + blockIdx.z*M*N (split-K), reduced in k_ln_red.
template <int BM, int BIAS, int GELU, int OUTBF16, int SPLITK>
__launch_bounds__(256, 2)
__global__ void k_gemm(const unsigned short* __restrict__ A,
                       const unsigned short* __restrict__ Bt,
                       const float* __restrict__ bias,
                       void* __restrict__ out,
                       int M, int N, int K) {
    constexpr int MF = BM / 32;                       // m-frags per wave
    constexpr int HALF = (BM + 128) * 64;             // bytes per stage buffer
    __shared__ char smem_raw[2 * HALF];

    int t = threadIdx.x;
    int bm = blockIdx.x, bn = blockIdx.y;
    int kc = (SPLITK > 1) ? blockIdx.z : 0;
    int KC = K / SPLITK;

    int rowA0 = bm * BM, rowB0 = bn * 128;
    int lane = t & 63, w = t >> 6;
    int wr = w >> 1, wc = w & 1;

    const unsigned short* ga0 = A  + (size_t)(rowA0 + (t >> 2)) * K + kc * KC + (t & 3) * 8;
    const unsigned short* ga1 = ga0 + (size_t)64 * K;
    const unsigned short* gb0 = Bt + (size_t)(rowB0 + (t >> 2)) * K + kc * KC + (t & 3) * 8;
    const unsigned short* gb1 = gb0 + (size_t)64 * K;

    auto stage = [&](int buf, int ktile) {
        char* dst = smem_raw + buf * HALF + t * 16;
        int kt = ktile * 32;
        GL2LDS(ga0 + kt, dst);
        if constexpr (BM == 128) GL2LDS(ga1 + kt, dst + 4096);
        char* dstB = dst + BM * 64;
        GL2LDS(gb0 + kt, dstB);
        GL2LDS(gb1 + kt, dstB + 4096);
    };

    f32x4_t acc[MF][4] = {};

    int rA = wr * (BM / 2) + (lane & 15);
    int rB = wc * 64 + (lane & 15);
    int kofs = (lane >> 4) * 8;

    const int NT = KC / 32;
    stage(0, 0);
    __syncthreads();
    int cur = 0;
    for (int kt = 0; kt < NT; kt++) {
        if (kt + 1 < NT) stage(cur ^ 1, kt + 1);   // prefetch overlaps compute
        const unsigned short* As = (const unsigned short*)(smem_raw + cur * HALF);
        const unsigned short* Bs = As + BM * 32;
        bf16x8_t a[MF], b[4];
#pragma unroll
        for (int m = 0; m < MF; m++)
            a[m] = *reinterpret_cast<const bf16x8_t*>(As + (rA + m * 16) * 32 + kofs);
#pragma unroll
        for (int n = 0; n < 4; n++)
            b[n] = *reinterpret_cast<const bf16x8_t*>(Bs + (rB + n * 16) * 32 + kofs);
#pragma unroll
        for (int m = 0; m < MF; m++)
#pragma unroll
            for (int n = 0; n < 4; n++)
                acc[m][n] = mfma16(a[m], b[n], acc[m][n]);
        __syncthreads();              // drains prefetch + protects buf reuse
        cur ^= 1;
    }

    if constexpr (OUTBF16) {
        int colBase = bn * 128 + wc * 64 + (lane & 15);
        int rowBase = bm * BM + wr * (BM / 2) + ((lane >> 4) << 2);
#pragma unroll
        for (int n = 0; n < 4; n++) {
            int col = colBase + n * 16;
            float bv = 0.f;
            if (BIAS) bv = bias[col];
#pragma unroll
            for (int m = 0; m < MF; m++) {
                int row0 = rowBase + m * 16;
#pragma unroll
                for (int r = 0; r < 4; r++) {
                    int row = row0 + r;
                    float v = acc[m][n][r] + bv;
                    if (GELU) v = 0.5f * v * (1.f + erff(v * 0.70710678118f));
                    ((unsigned short*)out)[(size_t)row * N + col] = f2bf(v);
                }
            }
        }
    } else {
        // f32 partials: LDS epilogue transpose, 256B-contiguous float4 stores.
        auto epi = (float (*)[16][65])smem_raw;
        float* op_base = (float*)out + (size_t)kc * M * N;
        int rowBase0 = bm * BM + wr * (BM / 2);
        int colBase0 = bn * 128 + wc * 64;
#pragma unroll
        for (int m = 0; m < MF; m++) {
#pragma unroll
            for (int n = 0; n < 4; n++)
#pragma unroll
                for (int r = 0; r < 4; r++)
                    epi[w][(lane >> 4) * 4 + r][n * 16 + (lane & 15)] = acc[m][n][r];
            __syncthreads();
#pragma unroll
            for (int rr = 0; rr < 4; rr++) {
                int lr = (lane >> 4) * 4 + rr;
                int grow = rowBase0 + m * 16 + lr;
                int gcol = colBase0 + (lane & 15) * 4;
                float4 v4 = *reinterpret_cast<float4*>(&epi[w][lr][(lane & 15) * 4]);
                *reinterpret_cast<float4*>(op_base + (size_t)grow * N + gcol) = v4;
            }
            __syncthreads();
        }
    }
}

// ---------------------------------------------------------------- lm-head GEMM
// 256x256 tile, BK=64, 512 thr (8 waves, 2M x 4N), deep pipeline:
// counted vmcnt(8) spanning raw s_barriers (T4), LDS XOR swizzle on reads
// with pre-swizzled global source (T2 + rule#21), setprio around MFMA (T5).
__launch_bounds__(512, 1)
__global__ void k_lm(const unsigned short* __restrict__ A,
                     const unsigned short* __restrict__ Bt,
                     float* __restrict__ out) {
    constexpr int K = 768;
    constexpr int NT = K / 64;                 // 12 K-tiles
    __shared__ char smem[131072];              // 2 x (A 32KB | B 32KB)

    int t = threadIdx.x;
    int bm = blockIdx.x, bn = blockIdx.y;      // natural order, bm fastest
    int lane = t & 63, w = t >> 6;
    int wm = w >> 2, wn = w & 3;               // 2 x 4 waves
    int q = lane >> 4, l15 = lane & 15, l7 = lane & 7;

    int srow = t >> 3;                         // 0..63 per issue
    int sslot = (t & 7) ^ (srow & 7);
    const unsigned short* gA = A  + (size_t)(bm * 256 + srow) * K + sslot * 8;
    const unsigned short* gB = Bt + (size_t)(bn * 256 + srow) * K + sslot * 8;

    auto stage = [&](int buf, int ktile) {
        char* dst = smem + buf * 65536 + t * 16;
        int ko = ktile * 64;
#pragma unroll
        for (int i = 0; i < 4; i++)
            GL2LDS(gA + (size_t)(i * 64) * K + ko, dst + i * 8192);
#pragma unroll
        for (int i = 0; i < 4; i++)
            GL2LDS(gB + (size_t)(i * 64) * K + ko, dst + 32768 + i * 8192);
    };

    f32x4_t acc[8][4] = {};

    stage(0, 0);
    int cur = 0;
    for (int kt = 0; kt < NT; kt++) {
        if (kt + 1 < NT) {
            stage(cur ^ 1, kt + 1);
            asm volatile("s_waitcnt vmcnt(8)" ::: "memory");
        } else {
            asm volatile("s_waitcnt vmcnt(0)" ::: "memory");
        }
        __builtin_amdgcn_s_barrier();
        asm volatile("" ::: "memory");
        const char* Ab = smem + cur * 65536;
        const char* Bb = Ab + 32768;

        bf16x8_t bfr[4][2];
#pragma unroll
        for (int nf = 0; nf < 4; nf++)
#pragma unroll
            for (int ks = 0; ks < 2; ks++) {
                int row = wn * 64 + nf * 16 + l15;
                int slot = (ks * 4 + q) ^ l7;
                bfr[nf][ks] = *reinterpret_cast<const bf16x8_t*>(Bb + row * 128 + slot * 16);
            }
#pragma unroll
        for (int p = 0; p < 4; p++) {
            bf16x8_t afr[2][2];
#pragma unroll
            for (int mi = 0; mi < 2; mi++)
#pragma unroll
                for (int ks = 0; ks < 2; ks++) {
                    int row = wm * 128 + (p * 2 + mi) * 16 + l15;
                    int slot = (ks * 4 + q) ^ l7;
                    afr[mi][ks] = *reinterpret_cast<const bf16x8_t*>(Ab + row * 128 + slot * 16);
                }
            asm volatile("s_waitcnt lgkmcnt(0)" ::: "memory");
            __builtin_amdgcn_sched_barrier(0);
            __builtin_amdgcn_s_setprio(1);
#pragma unroll
            for (int mi = 0; mi < 2; mi++)
#pragma unroll
                for (int nf = 0; nf < 4; nf++)
#pragma unroll
                    for (int ks = 0; ks < 2; ks++)
                        acc[p * 2 + mi][nf] = mfma16(afr[mi][ks], bfr[nf][ks], acc[p * 2 + mi][nf]);
            __builtin_amdgcn_s_setprio(0);
        }
        asm volatile("" ::: "memory");
        __builtin_amdgcn_s_barrier();
        cur ^= 1;
    }

    float* epi = (float*)smem + w * (16 * 68);
#pragma unroll
    for (int mf = 0; mf < 8; mf++) {
#pragma unroll
        for (int nf = 0; nf < 4; nf++)
#pragma unroll
            for (int r = 0; r < 4; r++)
                epi[(q * 4 + r) * 68 + nf * 16 + l15] = acc[mf][nf][r];
        asm volatile("s_waitcnt lgkmcnt(0)" ::: "memory");
#pragma unroll
        for (int rr = 0; rr < 4; rr++) {
            int lr = q * 4 + rr;
            int grow = bm * 256 + wm * 128 + mf * 16 + lr;
            int col0 = bn * 256 + wn * 64 + l15;
            float* op = out + (size_t)grow * 50257 + col0;
#pragma unroll
            for (int e = 0; e < 4; e++) {
                if (col0 + e * 16 < 50257) op[e * 16] = epi[lr * 68 + l15 + e * 16];
            }
        }
        asm volatile("s_waitcnt lgkmcnt(0)" ::: "memory");
    }
}

// ---------------------------------------------------------------- flash attention
// grid (16 q-tiles, 48 bh), 256 thr. Wave w owns 16 q-rows. KV tile = 64.
// V staged transposed+swizzled in LDS (shared by 4 waves); K direct from L2.
__launch_bounds__(256, 2)
__global__ void k_attn(const unsigned short* __restrict__ qkv, unsigned short* __restrict__ y) {
    __shared__ unsigned short Vt[4096];          // [d=64][key=64], XOR-swizzled
    __shared__ unsigned short Ps[4][16 * 72];    // per-wave P rows, stride 72

    int bh = blockIdx.y;
    int b = bh / 12, h = bh % 12;
    int qt = blockIdx.x;
    int t = threadIdx.x, lane = t & 63, w = t >> 6;
    const size_t ldq = 2304;
    const unsigned short* base = qkv + (size_t)b * 1024 * ldq + h * 64;

    bf16x8_t qf[2];
    int qrow = qt * 64 + w * 16 + (lane & 15);
#pragma unroll
    for (int kb = 0; kb < 2; kb++)
        qf[kb] = *reinterpret_cast<const bf16x8_t*>(base + (size_t)qrow * ldq + kb * 32 + (lane >> 4) * 8);

    f32x4_t o[4] = {};
    float mrow[4], lsum[4];
#pragma unroll
    for (int r = 0; r < 4; r++) { mrow[r] = -1e30f; lsum[r] = 0.f; }
    const float scale = 0.125f;

    for (int kt = 0; kt < 16; kt++) {
        {
            const unsigned short* vsrc = base + 1536 + (size_t)(kt * 64 + lane) * ldq + w * 16;
            union { uint4 v[2]; unsigned short e[16]; } vv;
            vv.v[0] = *reinterpret_cast<const uint4*>(vsrc);
            vv.v[1] = *reinterpret_cast<const uint4*>(vsrc + 8);
            __syncthreads();
#pragma unroll
            for (int j = 0; j < 16; j++) {
                int d = w * 16 + j;
                uint32_t byte = (uint32_t)(d * 128 + lane * 2) ^ (uint32_t)((d & 7) << 4);
                *(unsigned short*)((char*)Vt + byte) = vv.e[j];
            }
            __syncthreads();
        }
        f32x4_t s[4] = {};
#pragma unroll
        for (int kb = 0; kb < 2; kb++) {
#pragma unroll
            for (int n = 0; n < 4; n++) {
                const unsigned short* kp = base + 768 +
                    (size_t)(kt * 64 + n * 16 + (lane & 15)) * ldq + kb * 32 + (lane >> 4) * 8;
                bf16x8_t kf = *reinterpret_cast<const bf16x8_t*>(kp);
                s[n] = mfma16(qf[kb], kf, s[n]);
            }
        }
        float corr[4];
#pragma unroll
        for (int r = 0; r < 4; r++) {
            float mx = fmaxf(fmaxf(s[0][r], s[1][r]), fmaxf(s[2][r], s[3][r]));
#pragma unroll
            for (int o2 = 1; o2 < 16; o2 <<= 1) mx = fmaxf(mx, __shfl_xor(mx, o2));
            float mnew = fmaxf(mrow[r], mx * scale);
            corr[r] = __expf(mrow[r] - mnew);
            mrow[r] = mnew;
        }
        float psum[4] = {0.f, 0.f, 0.f, 0.f};
#pragma unroll
        for (int n = 0; n < 4; n++) {
#pragma unroll
            for (int r = 0; r < 4; r++) {
                float p = __expf(s[n][r] * scale - mrow[r]);
                psum[r] += p;
                int prow = (lane >> 4) * 4 + r;
                Ps[w][prow * 72 + n * 16 + (lane & 15)] = f2bf(p);
            }
        }
#pragma unroll
        for (int r = 0; r < 4; r++) {
            float ps = psum[r];
#pragma unroll
            for (int o2 = 1; o2 < 16; o2 <<= 1) ps += __shfl_xor(ps, o2);
            lsum[r] = lsum[r] * corr[r] + ps;
#pragma unroll
            for (int n = 0; n < 4; n++) o[n][r] *= corr[r];
        }
#pragma unroll
        for (int kb = 0; kb < 2; kb++) {
            bf16x8_t pf = *reinterpret_cast<const bf16x8_t*>(
                &Ps[w][(lane & 15) * 72 + kb * 32 + (lane >> 4) * 8]);
#pragma unroll
            for (int n = 0; n < 4; n++) {
                int d = n * 16 + (lane & 15);
                uint32_t byte = (uint32_t)(d * 128 + (kb * 32 + (lane >> 4) * 8) * 2)
                                ^ (uint32_t)((d & 7) << 4);
                bf16x8_t vf = *reinterpret_cast<const bf16x8_t*>((char*)Vt + byte);
                o[n] = mfma16(pf, vf, o[n]);
            }
        }
    }
#pragma unroll
    for (int n = 0; n < 4; n++) {
#pragma unroll
        for (int r = 0; r < 4; r++) {
            float val = o[n][r] / lsum[r];
            int row = qt * 64 + w * 16 + (lane >> 4) * 4 + r;
            y[((size_t)(b * 1024 + row)) * 768 + h * 64 + n * 16 + (lane & 15)] = f2bf(val);
        }
    }
}

// ---------------------------------------------------------------- host
extern "C" void kernel_launch(void* const* d_in, const int* in_sizes, int n_in,
                              void* d_out, int out_size, void* d_ws, size_t ws_size,
                              hipStream_t stream) {
    const int*   ids   = (const int*)d_in[0];
    const float* wte   = (const float*)d_in[1];
    const float* wpe   = (const float*)d_in[2];
    const float* ln1w  = (const float*)d_in[3];
    const float* ln1b  = (const float*)d_in[4];
    const float* attnw = (const float*)d_in[5];
    const float* attnb = (const float*)d_in[6];
    const float* atpw  = (const float*)d_in[7];
    const float* atpb  = (const float*)d_in[8];
    const float* ln2w  = (const float*)d_in[9];
    const float* ln2b  = (const float*)d_in[10];
    const float* fcw   = (const float*)d_in[11];
    const float* fcb   = (const float*)d_in[12];
    const float* pjw   = (const float*)d_in[13];
    const float* pjb   = (const float*)d_in[14];
    const float* lnfw  = (const float*)d_in[15];
    const float* lnfb  = (const float*)d_in[16];
    const float* lmw   = (const float*)d_in[17];
    float* out = (float*)d_out;

    char* ws = (char*)d_ws;
    size_t off = 0;
    auto alloc = [&](size_t bytes) -> void* {
        void* p = ws + off;
        off += (bytes + 255) & ~(size_t)255;
        return p;
    };
    float*          h      = (float*)alloc(4096ull * 768 * 4);
    unsigned short* x      = (unsigned short*)alloc(4096ull * 768 * 2);
    unsigned short* qkvb   = (unsigned short*)alloc(4096ull * 2304 * 2);
    unsigned short* y      = (unsigned short*)alloc(4096ull * 768 * 2);
    unsigned short* u      = (unsigned short*)alloc(4096ull * 3072 * 2);
    float*          part   = (float*)alloc(2ull * 4096 * 768 * 4);
    unsigned short* attnwT = (unsigned short*)alloc(12ull * 2304 * 768 * 2);
    unsigned short* atpwT  = (unsigned short*)alloc(12ull * 768 * 768 * 2);
    unsigned short* fcwT   = (unsigned short*)alloc(12ull * 3072 * 768 * 2);
    unsigned short* pjwT   = (unsigned short*)alloc(12ull * 768 * 3072 * 2);
    unsigned short* lmwT   = (unsigned short*)alloc(50432ull * 768 * 2);

    dim3 tb(32, 8);
    k_transpose<<<dim3(2304 / 32, 768 / 32, 12), tb, 0, stream>>>(attnw, attnwT, 768, 2304, 2304);
    k_transpose<<<dim3(768 / 32, 768 / 32, 12), tb, 0, stream>>>(atpw, atpwT, 768, 768, 768);
    k_transpose<<<dim3(3072 / 32, 768 / 32, 12), tb, 0, stream>>>(fcw, fcwT, 768, 3072, 3072);
    k_transpose<<<dim3(768 / 32, 3072 / 32, 12), tb, 0, stream>>>(pjw, pjwT, 3072, 768, 768);
    k_transpose<<<dim3(50432 / 32, 768 / 32, 1), tb, 0, stream>>>(lmw, lmwT, 768, 50257, 50432);

    k_embed<<<4096, 256, 0, stream>>>(ids, wte, wpe, h);
    k_ln<<<4096, 256, 0, stream>>>(h, ln1w, ln1b, x);     // layer-0 ln1

    for (int l = 0; l < 12; l++) {
        // qkv (plain bf16 out)
        k_gemm<128, 1, 0, 1, 1><<<dim3(32, 18), 256, 0, stream>>>(
            x, attnwT + (size_t)l * 2304 * 768, attnb + l * 2304, qkvb,
            4096, 2304, 768);
        k_attn<<<dim3(16, 48), 256, 0, stream>>>(qkvb, y);
        // atp: split-K=2 f32 partials
        k_gemm<64, 0, 0, 0, 2><<<dim3(64, 6, 2), 256, 0, stream>>>(
            y, atpwT + (size_t)l * 768 * 768, nullptr, part,
            4096, 768, 768);
        k_ln_red<<<4096, 256, 0, stream>>>(part, atpb + l * 768,
            ln2w + l * 768, ln2b + l * 768, h, x);
        // fc
        k_gemm<128, 1, 1, 1, 1><<<dim3(32, 24), 256, 0, stream>>>(
            x, fcwT + (size_t)l * 3072 * 768, fcb + l * 3072, u,
            4096, 3072, 768);
        // pj: split-K=2 f32 partials
        k_gemm<64, 0, 0, 0, 2><<<dim3(64, 6, 2), 256, 0, stream>>>(
            u, pjwT + (size_t)l * 768 * 3072, nullptr, part,
            4096, 768, 3072);
        const float* nw = (l < 11) ? ln1w + (l + 1) * 768 : lnfw;
        const float* nb = (l < 11) ? ln1b + (l + 1) * 768 : lnfb;
        k_ln_red<<<4096, 256, 0, stream>>>(part, pjb + l * 768, nw, nb, h, x);
    }
    k_lm<<<dim3(16, 197), 512, 0, stream>>>(x, lmwT, out);
}